// Round 14
// baseline (392.744 us; speedup 1.0000x reference)
//
#include <hip/hip_runtime.h>
#include <hip/hip_fp16.h>
#include <stdint.h>

#define DIN 96
#define DP 48
#define NPOS (48*48*48)   // 110592
#define NG 1728           // 12^3
#define WIN3 343
#define NCH 64
#define NC2 32

// ---------------------------------------------------------------------------
// PROBE ROUND: internal-repeat loops (idempotent) lift per-dispatch durations
// above the ~142us fill dispatches so rocprof top-5 shows REAL counters.
//   dwconv16h: rep=4   -> A = dur/4
//   pwk:       rep=16  -> B = dur/16
// Algorithm output identical to R13.
// ---------------------------------------------------------------------------

__global__ __launch_bounds__(256) void dwconv16h(
    const float* __restrict__ feat,   // [64][96][96][96]
    const float* __restrict__ dw_w,   // [64][27]
    const float* __restrict__ dw_b,   // [64]
    __half* __restrict__ dwout)       // [64][NPOS] fp16
{
    const int c   = blockIdx.y;
    const int idx = blockIdx.x * 256 + threadIdx.x;   // 0..6911
    const int t   = idx % 12;                         // w-quad (ow = 4t..4t+3)
    const int ohp = (idx / 12) % 24;                  // h-pair
    const int odp = idx / (12 * 24);                  // d-pair

    const float* fc = feat + (size_t)c * (DIN * DIN * DIN);
    const float* wc = dw_w + c * 27;
    float w[27];
    #pragma unroll
    for (int i = 0; i < 27; ++i) w[i] = wc[i];
    const float b = dw_b[c];

    #pragma unroll 1
    for (int rep = 0; rep < 4; ++rep) {
        float acc[2][2][4];
        #pragma unroll
        for (int a = 0; a < 2; ++a)
            #pragma unroll
            for (int bb = 0; bb < 2; ++bb)
                #pragma unroll
                for (int j = 0; j < 4; ++j) acc[a][bb][j] = 0.0f;

        #pragma unroll
        for (int dd = 0; dd < 5; ++dd) {
            const int id = 4 * odp - 1 + dd;
            if (id >= 0) {
                #pragma unroll
                for (int hh = 0; hh < 5; ++hh) {
                    const int ih = 4 * ohp - 1 + hh;
                    if (ih >= 0) {
                        const float* row = fc + ((size_t)id * DIN + ih) * DIN + 8 * t;
                        const float4 a4 = *(const float4*)(row);
                        const float4 b4 = *(const float4*)(row + 4);
                        const float  s  = (t > 0) ? row[-1] : 0.0f;
                        #pragma unroll
                        for (int dh = 0; dh < 2; ++dh) {
                            if ((dh == 0 && dd <= 2) || (dh == 1 && dd >= 2)) {
                                const int kd = dd - 2 * dh;
                                #pragma unroll
                                for (int hf = 0; hf < 2; ++hf) {
                                    if ((hf == 0 && hh <= 2) || (hf == 1 && hh >= 2)) {
                                        const int kh = hh - 2 * hf;
                                        const float w0 = w[(kd * 3 + kh) * 3 + 0];
                                        const float w1 = w[(kd * 3 + kh) * 3 + 1];
                                        const float w2 = w[(kd * 3 + kh) * 3 + 2];
                                        float* ac = acc[dh][hf];
                                        ac[0] = fmaf(s,    w0, fmaf(a4.x, w1, fmaf(a4.y, w2, ac[0])));
                                        ac[1] = fmaf(a4.y, w0, fmaf(a4.z, w1, fmaf(a4.w, w2, ac[1])));
                                        ac[2] = fmaf(a4.w, w0, fmaf(b4.x, w1, fmaf(b4.y, w2, ac[2])));
                                        ac[3] = fmaf(b4.y, w0, fmaf(b4.z, w1, fmaf(b4.w, w2, ac[3])));
                                    }
                                }
                            }
                        }
                    }
                }
            }
        }

        const size_t base = (size_t)c * NPOS + (((size_t)(2 * odp) * DP + 2 * ohp) * DP) + 4 * t;
        #pragma unroll
        for (int dh = 0; dh < 2; ++dh)
            #pragma unroll
            for (int hf = 0; hf < 2; ++hf) {
                const float* ac = acc[dh][hf];
                float2 pk;
                ((__half2*)&pk)[0] = __floats2half2_rn(ac[0] + b, ac[1] + b);
                ((__half2*)&pk)[1] = __floats2half2_rn(ac[2] + b, ac[3] + b);
                *(float2*)(dwout + base + (size_t)dh * DP * DP + (size_t)hf * DP) = pk;
            }
    }
}

__global__ __launch_bounds__(256) void pwk(
    const __half* __restrict__ dwout, // [64][NPOS] fp16
    const float* __restrict__ pw_w,   // [32][64]
    const float* __restrict__ pw_b,   // [32]
    const float* __restrict__ k_w,    // [64][32]
    const float* __restrict__ v_w,    // [64][32]
    const float* __restrict__ out_w,  // [3][64]
    float* __restrict__ VP8)          // [NPOS][8]
{
    __shared__ float swT[NCH * NC2];
    __shared__ float sb[NC2];
    __shared__ float WC[8][NC2];
    __shared__ float f2s[128][33];
    const int tid = threadIdx.x;

    for (int i = tid; i < NCH * NC2; i += 256) {
        const int o = i & 31, c = i >> 5;
        swT[i] = pw_w[o * NCH + c];
    }
    if (tid < NC2) sb[tid] = pw_b[tid];
    if (tid < 64) {
        const int h = tid >> 5, o = tid & 31;
        WC[h][o] = k_w[(h * 32) * NC2 + o] * 0.17677669529663687f;
    } else {
        const int r = (tid - 64) >> 5, k = (tid - 64) & 31;
        const int h = r / 3, oo = r % 3;
        float a = 0.f;
        #pragma unroll
        for (int c = 0; c < NC2; ++c)
            a = fmaf(out_w[oo * NCH + h * 32 + c], v_w[(h * 32 + c) * NC2 + k], a);
        WC[2 + r][k] = a;
    }
    __syncthreads();

    const int oq = tid & 7;
    const int p4 = tid >> 3;
    const size_t pos0 = (size_t)blockIdx.x * 128;

    #pragma unroll 1
    for (int rep = 0; rep < 16; ++rep) {
        float acc[4][4];
        #pragma unroll
        for (int i = 0; i < 4; ++i) {
            const float b = sb[oq * 4 + i];
            #pragma unroll
            for (int j = 0; j < 4; ++j) acc[i][j] = b;
        }

        const __half* xp = dwout + pos0 + 4 * (size_t)p4;
        #pragma unroll 4
        for (int c = 0; c < NCH; ++c) {
            const float2 raw = *(const float2*)(xp + (size_t)c * NPOS);
            const float2 x01 = __half22float2(((const __half2*)&raw)[0]);
            const float2 x23 = __half22float2(((const __half2*)&raw)[1]);
            const float4 w4 = *(const float4*)(swT + c * NC2 + oq * 4);
            const float xs[4] = {x01.x, x01.y, x23.x, x23.y};
            const float ws[4] = {w4.x, w4.y, w4.z, w4.w};
            #pragma unroll
            for (int i = 0; i < 4; ++i)
                #pragma unroll
                for (int j = 0; j < 4; ++j)
                    acc[i][j] = fmaf(ws[i], xs[j], acc[i][j]);
        }

        #pragma unroll
        for (int j = 0; j < 4; ++j) {
            const int pl = p4 * 4 + j;
            #pragma unroll
            for (int i = 0; i < 4; ++i)
                f2s[pl][oq * 4 + i] = fmaxf(acc[i][j], 0.f);
        }
        __syncthreads();

        const int q  = tid & 1;
        const int pl = tid >> 1;
        float a8[4] = {0.f, 0.f, 0.f, 0.f};
        #pragma unroll 8
        for (int o = 0; o < NC2; ++o) {
            const float x = f2s[pl][o];
            #pragma unroll
            for (int r = 0; r < 4; ++r)
                a8[r] = fmaf(WC[q * 4 + r][o], x, a8[r]);
        }
        *(float4*)(VP8 + (pos0 + pl) * 8 + q * 4) = make_float4(a8[0], a8[1], a8[2], a8[3]);
        __syncthreads();   // protect f2s before next rep overwrites
    }
}

__global__ __launch_bounds__(256) void attn_vp(
    const float* __restrict__ VP8,    // [NPOS][8]
    const float* __restrict__ out_b,  // [3]
    float* __restrict__ out)          // [3][NG]
{
    const int lo_t[12] = {0,1,5,9,14,18,22,26,31,35,39,44};
    const int hi_t[12] = {4,8,12,16,21,25,29,33,38,42,46,48};

    const int g    = blockIdx.x;
    const int tid  = threadIdx.x;
    const int lane = tid & 63;
    const int wv   = tid >> 6;

    const int gz = g % 12, gy = (g / 12) % 12, gx = g / 144;
    const int lox = lo_t[gx], hix = hi_t[gx];
    const int loy = lo_t[gy], hiy = hi_t[gy];
    const int loz = lo_t[gz], hiz = hi_t[gz];

    const float NEG_INF = -__builtin_inff();

    float4 lo0, hi0, lo1, hi1;
    {
        const int s = tid;
        const int kd = s / 49, kh = (s / 7) % 7, kw = s % 7;
        const int ix = lox + kd, iy = loy + kh, iz = loz + kw;
        if (ix < hix && iy < hiy && iz < hiz) {
            const int fv = (ix * DP + iy) * DP + iz;
            const float4* p = (const float4*)(VP8 + (size_t)fv * 8);
            lo0 = p[0]; hi0 = p[1];
        } else {
            lo0 = make_float4(NEG_INF, NEG_INF, 0.f, 0.f);
            hi0 = make_float4(0.f, 0.f, 0.f, 0.f);
        }
    }
    {
        const int s = tid + 256;
        lo1 = make_float4(NEG_INF, NEG_INF, 0.f, 0.f);
        hi1 = make_float4(0.f, 0.f, 0.f, 0.f);
        if (s < WIN3) {
            const int kd = s / 49, kh = (s / 7) % 7, kw = s % 7;
            const int ix = lox + kd, iy = loy + kh, iz = loz + kw;
            if (ix < hix && iy < hiy && iz < hiz) {
                const int fv = (ix * DP + iy) * DP + iz;
                const float4* p = (const float4*)(VP8 + (size_t)fv * 8);
                lo1 = p[0]; hi1 = p[1];
            }
        }
    }

    __shared__ float sred[4][8];

    float m0 = fmaxf(lo0.x, lo1.x);
    float m1 = fmaxf(lo0.y, lo1.y);
    #pragma unroll
    for (int off = 32; off; off >>= 1) {
        m0 = fmaxf(m0, __shfl_xor(m0, off));
        m1 = fmaxf(m1, __shfl_xor(m1, off));
    }
    if (lane == 0) { sred[wv][0] = m0; sred[wv][1] = m1; }
    __syncthreads();
    const float g0 = fmaxf(fmaxf(sred[0][0], sred[1][0]), fmaxf(sred[2][0], sred[3][0]));
    const float g1 = fmaxf(fmaxf(sred[0][1], sred[1][1]), fmaxf(sred[2][1], sred[3][1]));
    __syncthreads();

    const float e00 = expf(lo0.x - g0), e01 = expf(lo0.y - g1);
    const float e10 = expf(lo1.x - g0), e11 = expf(lo1.y - g1);

    float acc[8];
    acc[0] = e00 + e10;
    acc[1] = e01 + e11;
    acc[2] = e00 * lo0.z + e10 * lo1.z;
    acc[3] = e00 * lo0.w + e10 * lo1.w;
    acc[4] = e00 * hi0.x + e10 * hi1.x;
    acc[5] = e01 * hi0.y + e11 * hi1.y;
    acc[6] = e01 * hi0.z + e11 * hi1.z;
    acc[7] = e01 * hi0.w + e11 * hi1.w;

    #pragma unroll
    for (int j = 0; j < 8; ++j) {
        #pragma unroll
        for (int off = 32; off; off >>= 1) acc[j] += __shfl_xor(acc[j], off);
    }
    if (lane == 0) {
        #pragma unroll
        for (int j = 0; j < 8; ++j) sred[wv][j] = acc[j];
    }
    __syncthreads();

    if (tid < 3) {
        const float s0 = sred[0][0] + sred[1][0] + sred[2][0] + sred[3][0];
        const float s1 = sred[0][1] + sred[1][1] + sred[2][1] + sred[3][1];
        const float a0 = sred[0][2 + tid] + sred[1][2 + tid] + sred[2][2 + tid] + sred[3][2 + tid];
        const float a1 = sred[0][5 + tid] + sred[1][5 + tid] + sred[2][5 + tid] + sred[3][5 + tid];
        out[tid * NG + g] = out_b[tid] + a0 / s0 + a1 / s1;
    }
}

// ---------------------------------------------------------------------------
extern "C" void kernel_launch(void* const* d_in, const int* in_sizes, int n_in,
                              void* d_out, int out_size, void* d_ws, size_t ws_size,
                              hipStream_t stream) {
    const float* feat  = (const float*)d_in[0];
    const float* dw_w  = (const float*)d_in[1];
    const float* dw_b  = (const float*)d_in[2];
    const float* pw_w  = (const float*)d_in[3];
    const float* pw_b  = (const float*)d_in[4];
    const float* k_w   = (const float*)d_in[5];
    const float* v_w   = (const float*)d_in[6];
    const float* out_w = (const float*)d_in[7];
    const float* out_b = (const float*)d_in[8];
    float* out = (float*)d_out;

    __half* dwout = (__half*)d_ws;                              // [64][NPOS] 14 MB
    float*  VP8   = (float*)(dwout + (size_t)NCH * NPOS);       // [NPOS][8] 3.5 MB

    hipLaunchKernelGGL(dwconv16h, dim3(27, NCH), dim3(256), 0, stream,
                       feat, dw_w, dw_b, dwout);
    hipLaunchKernelGGL(pwk, dim3(NPOS / 128), dim3(256), 0, stream,
                       dwout, pw_w, pw_b, k_w, v_w, out_w, VP8);
    hipLaunchKernelGGL(attn_vp, dim3(NG), dim3(256), 0, stream,
                       VP8, out_b, out);
}

// Round 15
// 76.912 us; speedup vs baseline: 5.1064x; 5.1064x over previous
//
#include <hip/hip_runtime.h>
#include <hip/hip_fp16.h>
#include <stdint.h>

#define DIN 96
#define DP 48
#define NPOS (48*48*48)   // 110592
#define NG 1728           // 12^3
#define WIN3 343
#define NCH 64
#define NC2 32

// ---------------------------------------------------------------------------
// Kernel A: depthwise 3x3x3 stride-2 pad-1 conv + bias -> dwout[c][pos] fp16
// PROVEN SHAPE (R8 probe: 48.7us): 2(d) x 1(h) x 4(w) = 8 outputs/thread,
// grid (54, 64) = 3456 blocks, 13824 threads/channel.
// ---------------------------------------------------------------------------
__global__ __launch_bounds__(256) void dwconv8h(
    const float* __restrict__ feat,   // [64][96][96][96]
    const float* __restrict__ dw_w,   // [64][27]
    const float* __restrict__ dw_b,   // [64]
    __half* __restrict__ dwout)       // [64][NPOS] fp16
{
    const int c   = blockIdx.y;
    const int idx = blockIdx.x * 256 + threadIdx.x;   // 0..13823
    const int t   = idx % 12;                         // w-quad (ow = 4t..4t+3)
    const int oh  = (idx / 12) % 48;
    const int odp = idx / (12 * 48);                  // d-pair (od = 2odp,2odp+1)

    const float* fc = feat + (size_t)c * (DIN * DIN * DIN);
    const float* wc = dw_w + c * 27;
    float w[27];
    #pragma unroll
    for (int i = 0; i < 27; ++i) w[i] = wc[i];        // wave-uniform

    float acc[2][4];
    #pragma unroll
    for (int i = 0; i < 2; ++i)
        #pragma unroll
        for (int j = 0; j < 4; ++j) acc[i][j] = 0.0f;

    #pragma unroll
    for (int dd = 0; dd < 5; ++dd) {
        const int id = 4 * odp - 1 + dd;              // input plane
        if (id >= 0) {
            #pragma unroll
            for (int kh = 0; kh < 3; ++kh) {
                const int ih = 2 * oh - 1 + kh;       // input row
                if (ih >= 0) {
                    const float* row = fc + ((size_t)id * DIN + ih) * DIN + 8 * t;
                    const float4 a4 = *(const float4*)(row);
                    const float4 b4 = *(const float4*)(row + 4);
                    const float  s  = (t > 0) ? row[-1] : 0.0f;   // w = 8t-1 (pad 0)
                    #pragma unroll
                    for (int half = 0; half < 2; ++half) {
                        if ((half == 0 && dd <= 2) || (half == 1 && dd >= 2)) {
                            const int kd = (half == 0) ? dd : dd - 2;
                            const float w0 = w[(kd * 3 + kh) * 3 + 0];
                            const float w1 = w[(kd * 3 + kh) * 3 + 1];
                            const float w2 = w[(kd * 3 + kh) * 3 + 2];
                            acc[half][0] = fmaf(s,    w0, fmaf(a4.x, w1, fmaf(a4.y, w2, acc[half][0])));
                            acc[half][1] = fmaf(a4.y, w0, fmaf(a4.z, w1, fmaf(a4.w, w2, acc[half][1])));
                            acc[half][2] = fmaf(a4.w, w0, fmaf(b4.x, w1, fmaf(b4.y, w2, acc[half][2])));
                            acc[half][3] = fmaf(b4.y, w0, fmaf(b4.z, w1, fmaf(b4.w, w2, acc[half][3])));
                        }
                    }
                }
            }
        }
    }

    const float b = dw_b[c];
    const size_t base = (size_t)c * NPOS + (((size_t)(2 * odp) * DP + oh) * DP) + 4 * t;
    {
        float2 pk;
        ((__half2*)&pk)[0] = __floats2half2_rn(acc[0][0] + b, acc[0][1] + b);
        ((__half2*)&pk)[1] = __floats2half2_rn(acc[0][2] + b, acc[0][3] + b);
        *(float2*)(dwout + base) = pk;
    }
    {
        float2 pk;
        ((__half2*)&pk)[0] = __floats2half2_rn(acc[1][0] + b, acc[1][1] + b);
        ((__half2*)&pk)[1] = __floats2half2_rn(acc[1][2] + b, acc[1][3] + b);
        *(float2*)(dwout + base + DP * DP) = pk;
    }
}

// ---------------------------------------------------------------------------
// Kernel B (fused pw1+kvp8, fp16 input): pointwise(64->32)+ReLU then
// prefolded K/V-projection -> VP8[NPOS][8].  (measured ~7.7us — near floor)
//   VP8 row = { k0, k1, vp[h0][o0..2], vp[h1][o0..2] }
// ---------------------------------------------------------------------------
__global__ __launch_bounds__(256) void pwk(
    const __half* __restrict__ dwout, // [64][NPOS] fp16
    const float* __restrict__ pw_w,   // [32][64]
    const float* __restrict__ pw_b,   // [32]
    const float* __restrict__ k_w,    // [64][32]
    const float* __restrict__ v_w,    // [64][32]
    const float* __restrict__ out_w,  // [3][64]
    float* __restrict__ VP8)          // [NPOS][8]
{
    __shared__ float swT[NCH * NC2];  // swT[c*32+o] = pw_w[o*64+c]
    __shared__ float sb[NC2];
    __shared__ float WC[8][NC2];
    __shared__ float f2s[128][33];
    const int tid = threadIdx.x;

    for (int i = tid; i < NCH * NC2; i += 256) {
        const int o = i & 31, c = i >> 5;
        swT[i] = pw_w[o * NCH + c];
    }
    if (tid < NC2) sb[tid] = pw_b[tid];
    if (tid < 64) {                   // K rows, prescaled
        const int h = tid >> 5, o = tid & 31;
        WC[h][o] = k_w[(h * 32) * NC2 + o] * 0.17677669529663687f;
    } else {                          // W2 rows, r=0..5
        const int r = (tid - 64) >> 5, k = (tid - 64) & 31;
        const int h = r / 3, oo = r % 3;
        float a = 0.f;
        #pragma unroll
        for (int c = 0; c < NC2; ++c)
            a = fmaf(out_w[oo * NCH + h * 32 + c], v_w[(h * 32 + c) * NC2 + k], a);
        WC[2 + r][k] = a;
    }
    __syncthreads();

    // ---- phase 1: pointwise, 4 out-ch x 4 positions per thread ----
    const int oq = tid & 7;           // out-ch group: 4*oq .. 4*oq+3
    const int p4 = tid >> 3;          // local position quad 0..31
    const size_t pos0 = (size_t)blockIdx.x * 128;

    float acc[4][4];                  // [ch][pos]
    #pragma unroll
    for (int i = 0; i < 4; ++i) {
        const float b = sb[oq * 4 + i];
        #pragma unroll
        for (int j = 0; j < 4; ++j) acc[i][j] = b;
    }

    const __half* xp = dwout + pos0 + 4 * (size_t)p4;
    #pragma unroll 4
    for (int c = 0; c < NCH; ++c) {
        const float2 raw = *(const float2*)(xp + (size_t)c * NPOS);
        const float2 x01 = __half22float2(((const __half2*)&raw)[0]);
        const float2 x23 = __half22float2(((const __half2*)&raw)[1]);
        const float4 w4 = *(const float4*)(swT + c * NC2 + oq * 4);
        const float xs[4] = {x01.x, x01.y, x23.x, x23.y};
        const float ws[4] = {w4.x, w4.y, w4.z, w4.w};
        #pragma unroll
        for (int i = 0; i < 4; ++i)
            #pragma unroll
            for (int j = 0; j < 4; ++j)
                acc[i][j] = fmaf(ws[i], xs[j], acc[i][j]);
    }

    #pragma unroll
    for (int j = 0; j < 4; ++j) {
        const int pl = p4 * 4 + j;
        #pragma unroll
        for (int i = 0; i < 4; ++i)
            f2s[pl][oq * 4 + i] = fmaxf(acc[i][j], 0.f);
    }
    __syncthreads();

    // ---- phase 2: 2 threads per position, 4 VP8 outputs each ----
    const int q  = tid & 1;           // output group q*4..q*4+3
    const int pl = tid >> 1;          // local position 0..127
    float a8[4] = {0.f, 0.f, 0.f, 0.f};
    #pragma unroll 8
    for (int o = 0; o < NC2; ++o) {
        const float x = f2s[pl][o];
        #pragma unroll
        for (int r = 0; r < 4; ++r)
            a8[r] = fmaf(WC[q * 4 + r][o], x, a8[r]);
    }
    *(float4*)(VP8 + (pos0 + pl) * 8 + q * 4) = make_float4(a8[0], a8[1], a8[2], a8[3]);
}

// ---------------------------------------------------------------------------
// Kernel C: windowed attention from VP8 (unchanged).
// ---------------------------------------------------------------------------
__global__ __launch_bounds__(256) void attn_vp(
    const float* __restrict__ VP8,    // [NPOS][8]
    const float* __restrict__ out_b,  // [3]
    float* __restrict__ out)          // [3][NG]
{
    const int lo_t[12] = {0,1,5,9,14,18,22,26,31,35,39,44};
    const int hi_t[12] = {4,8,12,16,21,25,29,33,38,42,46,48};

    const int g    = blockIdx.x;
    const int tid  = threadIdx.x;
    const int lane = tid & 63;
    const int wv   = tid >> 6;

    const int gz = g % 12, gy = (g / 12) % 12, gx = g / 144;
    const int lox = lo_t[gx], hix = hi_t[gx];
    const int loy = lo_t[gy], hiy = hi_t[gy];
    const int loz = lo_t[gz], hiz = hi_t[gz];

    const float NEG_INF = -__builtin_inff();

    float4 lo0, hi0, lo1, hi1;
    {
        const int s = tid;
        const int kd = s / 49, kh = (s / 7) % 7, kw = s % 7;
        const int ix = lox + kd, iy = loy + kh, iz = loz + kw;
        if (ix < hix && iy < hiy && iz < hiz) {
            const int fv = (ix * DP + iy) * DP + iz;
            const float4* p = (const float4*)(VP8 + (size_t)fv * 8);
            lo0 = p[0]; hi0 = p[1];
        } else {
            lo0 = make_float4(NEG_INF, NEG_INF, 0.f, 0.f);
            hi0 = make_float4(0.f, 0.f, 0.f, 0.f);
        }
    }
    {
        const int s = tid + 256;
        lo1 = make_float4(NEG_INF, NEG_INF, 0.f, 0.f);
        hi1 = make_float4(0.f, 0.f, 0.f, 0.f);
        if (s < WIN3) {
            const int kd = s / 49, kh = (s / 7) % 7, kw = s % 7;
            const int ix = lox + kd, iy = loy + kh, iz = loz + kw;
            if (ix < hix && iy < hiy && iz < hiz) {
                const int fv = (ix * DP + iy) * DP + iz;
                const float4* p = (const float4*)(VP8 + (size_t)fv * 8);
                lo1 = p[0]; hi1 = p[1];
            }
        }
    }

    __shared__ float sred[4][8];

    float m0 = fmaxf(lo0.x, lo1.x);
    float m1 = fmaxf(lo0.y, lo1.y);
    #pragma unroll
    for (int off = 32; off; off >>= 1) {
        m0 = fmaxf(m0, __shfl_xor(m0, off));
        m1 = fmaxf(m1, __shfl_xor(m1, off));
    }
    if (lane == 0) { sred[wv][0] = m0; sred[wv][1] = m1; }
    __syncthreads();
    const float g0 = fmaxf(fmaxf(sred[0][0], sred[1][0]), fmaxf(sred[2][0], sred[3][0]));
    const float g1 = fmaxf(fmaxf(sred[0][1], sred[1][1]), fmaxf(sred[2][1], sred[3][1]));
    __syncthreads();

    const float e00 = expf(lo0.x - g0), e01 = expf(lo0.y - g1);
    const float e10 = expf(lo1.x - g0), e11 = expf(lo1.y - g1);

    float acc[8];
    acc[0] = e00 + e10;
    acc[1] = e01 + e11;
    acc[2] = e00 * lo0.z + e10 * lo1.z;
    acc[3] = e00 * lo0.w + e10 * lo1.w;
    acc[4] = e00 * hi0.x + e10 * hi1.x;
    acc[5] = e01 * hi0.y + e11 * hi1.y;
    acc[6] = e01 * hi0.z + e11 * hi1.z;
    acc[7] = e01 * hi0.w + e11 * hi1.w;

    #pragma unroll
    for (int j = 0; j < 8; ++j) {
        #pragma unroll
        for (int off = 32; off; off >>= 1) acc[j] += __shfl_xor(acc[j], off);
    }
    if (lane == 0) {
        #pragma unroll
        for (int j = 0; j < 8; ++j) sred[wv][j] = acc[j];
    }
    __syncthreads();

    if (tid < 3) {
        const float s0 = sred[0][0] + sred[1][0] + sred[2][0] + sred[3][0];
        const float s1 = sred[0][1] + sred[1][1] + sred[2][1] + sred[3][1];
        const float a0 = sred[0][2 + tid] + sred[1][2 + tid] + sred[2][2 + tid] + sred[3][2 + tid];
        const float a1 = sred[0][5 + tid] + sred[1][5 + tid] + sred[2][5 + tid] + sred[3][5 + tid];
        out[tid * NG + g] = out_b[tid] + a0 / s0 + a1 / s1;
    }
}

// ---------------------------------------------------------------------------
extern "C" void kernel_launch(void* const* d_in, const int* in_sizes, int n_in,
                              void* d_out, int out_size, void* d_ws, size_t ws_size,
                              hipStream_t stream) {
    const float* feat  = (const float*)d_in[0];
    const float* dw_w  = (const float*)d_in[1];
    const float* dw_b  = (const float*)d_in[2];
    const float* pw_w  = (const float*)d_in[3];
    const float* pw_b  = (const float*)d_in[4];
    const float* k_w   = (const float*)d_in[5];
    const float* v_w   = (const float*)d_in[6];
    const float* out_w = (const float*)d_in[7];
    const float* out_b = (const float*)d_in[8];
    float* out = (float*)d_out;

    __half* dwout = (__half*)d_ws;                              // [64][NPOS] 14 MB
    float*  VP8   = (float*)(dwout + (size_t)NCH * NPOS);       // [NPOS][8] 3.5 MB

    hipLaunchKernelGGL(dwconv8h, dim3(54, NCH), dim3(256), 0, stream,
                       feat, dw_w, dw_b, dwout);
    hipLaunchKernelGGL(pwk, dim3(NPOS / 128), dim3(256), 0, stream,   // 864 blocks
                       dwout, pw_w, pw_b, k_w, v_w, out_w, VP8);
    hipLaunchKernelGGL(attn_vp, dim3(NG), dim3(256), 0, stream,
                       VP8, out_b, out);
}

// Round 16
// 75.403 us; speedup vs baseline: 5.2086x; 1.0200x over previous
//
#include <hip/hip_runtime.h>
#include <hip/hip_fp16.h>
#include <stdint.h>

#define DIN 96
#define DP 48
#define NPOS (48*48*48)   // 110592
#define NG 1728           // 12^3
#define WIN3 343
#define NCH 64
#define NC2 32

// ---------------------------------------------------------------------------
// Kernel A: depthwise 3x3x3 stride-2 pad-1 conv + bias -> dwout[c][pos] fp16
// 2(d) x 1(h) x 4(w) = 8 outputs/thread; 3456 blocks (1-D grid).
// XCD-chunked swizzle: each of the 8 XCDs owns 432 consecutive logical
// blocks (= 8 complete channel slabs) so halo-row reuse stays in its L2.
// ---------------------------------------------------------------------------
__global__ __launch_bounds__(256) void dwconv8h(
    const float* __restrict__ feat,   // [64][96][96][96]
    const float* __restrict__ dw_w,   // [64][27]
    const float* __restrict__ dw_b,   // [64]
    __half* __restrict__ dwout)       // [64][NPOS] fp16
{
    // bijective chunked XCD swizzle (nwg=3456, 3456%8==0)
    const int bid  = blockIdx.x;
    const int orig = (bid & 7) * 432 + (bid >> 3);
    const int c    = orig / 54;
    const int bx   = orig % 54;

    const int idx = bx * 256 + threadIdx.x;           // 0..13823
    const int t   = idx % 12;                         // w-quad (ow = 4t..4t+3)
    const int oh  = (idx / 12) % 48;
    const int odp = idx / (12 * 48);                  // d-pair (od = 2odp,2odp+1)

    const float* fc = feat + (size_t)c * (DIN * DIN * DIN);
    const float* wc = dw_w + c * 27;
    float w[27];
    #pragma unroll
    for (int i = 0; i < 27; ++i) w[i] = wc[i];        // wave-uniform

    float acc[2][4];
    #pragma unroll
    for (int i = 0; i < 2; ++i)
        #pragma unroll
        for (int j = 0; j < 4; ++j) acc[i][j] = 0.0f;

    #pragma unroll
    for (int dd = 0; dd < 5; ++dd) {
        const int id = 4 * odp - 1 + dd;              // input plane
        if (id >= 0) {
            #pragma unroll
            for (int kh = 0; kh < 3; ++kh) {
                const int ih = 2 * oh - 1 + kh;       // input row
                if (ih >= 0) {
                    const float* row = fc + ((size_t)id * DIN + ih) * DIN + 8 * t;
                    const float4 a4 = *(const float4*)(row);
                    const float4 b4 = *(const float4*)(row + 4);
                    const float  s  = (t > 0) ? row[-1] : 0.0f;   // w = 8t-1 (pad 0)
                    #pragma unroll
                    for (int half = 0; half < 2; ++half) {
                        if ((half == 0 && dd <= 2) || (half == 1 && dd >= 2)) {
                            const int kd = (half == 0) ? dd : dd - 2;
                            const float w0 = w[(kd * 3 + kh) * 3 + 0];
                            const float w1 = w[(kd * 3 + kh) * 3 + 1];
                            const float w2 = w[(kd * 3 + kh) * 3 + 2];
                            acc[half][0] = fmaf(s,    w0, fmaf(a4.x, w1, fmaf(a4.y, w2, acc[half][0])));
                            acc[half][1] = fmaf(a4.y, w0, fmaf(a4.z, w1, fmaf(a4.w, w2, acc[half][1])));
                            acc[half][2] = fmaf(a4.w, w0, fmaf(b4.x, w1, fmaf(b4.y, w2, acc[half][2])));
                            acc[half][3] = fmaf(b4.y, w0, fmaf(b4.z, w1, fmaf(b4.w, w2, acc[half][3])));
                        }
                    }
                }
            }
        }
    }

    const float b = dw_b[c];
    const size_t base = (size_t)c * NPOS + (((size_t)(2 * odp) * DP + oh) * DP) + 4 * t;
    {
        float2 pk;
        ((__half2*)&pk)[0] = __floats2half2_rn(acc[0][0] + b, acc[0][1] + b);
        ((__half2*)&pk)[1] = __floats2half2_rn(acc[0][2] + b, acc[0][3] + b);
        *(float2*)(dwout + base) = pk;
    }
    {
        float2 pk;
        ((__half2*)&pk)[0] = __floats2half2_rn(acc[1][0] + b, acc[1][1] + b);
        ((__half2*)&pk)[1] = __floats2half2_rn(acc[1][2] + b, acc[1][3] + b);
        *(float2*)(dwout + base + DP * DP) = pk;
    }
}

// ---------------------------------------------------------------------------
// Kernel B (fused pw1+kvp8, fp16 input): pointwise(64->32)+ReLU then
// prefolded K/V-projection -> VP8[NPOS][8].  (~7.7us measured — near floor)
// ---------------------------------------------------------------------------
__global__ __launch_bounds__(256) void pwk(
    const __half* __restrict__ dwout, // [64][NPOS] fp16
    const float* __restrict__ pw_w,   // [32][64]
    const float* __restrict__ pw_b,   // [32]
    const float* __restrict__ k_w,    // [64][32]
    const float* __restrict__ v_w,    // [64][32]
    const float* __restrict__ out_w,  // [3][64]
    float* __restrict__ VP8)          // [NPOS][8]
{
    __shared__ float swT[NCH * NC2];  // swT[c*32+o] = pw_w[o*64+c]
    __shared__ float sb[NC2];
    __shared__ float WC[8][NC2];
    __shared__ float f2s[128][33];
    const int tid = threadIdx.x;

    for (int i = tid; i < NCH * NC2; i += 256) {
        const int o = i & 31, c = i >> 5;
        swT[i] = pw_w[o * NCH + c];
    }
    if (tid < NC2) sb[tid] = pw_b[tid];
    if (tid < 64) {                   // K rows, prescaled
        const int h = tid >> 5, o = tid & 31;
        WC[h][o] = k_w[(h * 32) * NC2 + o] * 0.17677669529663687f;
    } else {                          // W2 rows, r=0..5
        const int r = (tid - 64) >> 5, k = (tid - 64) & 31;
        const int h = r / 3, oo = r % 3;
        float a = 0.f;
        #pragma unroll
        for (int c = 0; c < NC2; ++c)
            a = fmaf(out_w[oo * NCH + h * 32 + c], v_w[(h * 32 + c) * NC2 + k], a);
        WC[2 + r][k] = a;
    }
    __syncthreads();

    const int oq = tid & 7;           // out-ch group: 4*oq .. 4*oq+3
    const int p4 = tid >> 3;          // local position quad 0..31
    const size_t pos0 = (size_t)blockIdx.x * 128;

    float acc[4][4];                  // [ch][pos]
    #pragma unroll
    for (int i = 0; i < 4; ++i) {
        const float b = sb[oq * 4 + i];
        #pragma unroll
        for (int j = 0; j < 4; ++j) acc[i][j] = b;
    }

    const __half* xp = dwout + pos0 + 4 * (size_t)p4;
    #pragma unroll 4
    for (int c = 0; c < NCH; ++c) {
        const float2 raw = *(const float2*)(xp + (size_t)c * NPOS);
        const float2 x01 = __half22float2(((const __half2*)&raw)[0]);
        const float2 x23 = __half22float2(((const __half2*)&raw)[1]);
        const float4 w4 = *(const float4*)(swT + c * NC2 + oq * 4);
        const float xs[4] = {x01.x, x01.y, x23.x, x23.y};
        const float ws[4] = {w4.x, w4.y, w4.z, w4.w};
        #pragma unroll
        for (int i = 0; i < 4; ++i)
            #pragma unroll
            for (int j = 0; j < 4; ++j)
                acc[i][j] = fmaf(ws[i], xs[j], acc[i][j]);
    }

    #pragma unroll
    for (int j = 0; j < 4; ++j) {
        const int pl = p4 * 4 + j;
        #pragma unroll
        for (int i = 0; i < 4; ++i)
            f2s[pl][oq * 4 + i] = fmaxf(acc[i][j], 0.f);
    }
    __syncthreads();

    const int q  = tid & 1;           // output group q*4..q*4+3
    const int pl = tid >> 1;          // local position 0..127
    float a8[4] = {0.f, 0.f, 0.f, 0.f};
    #pragma unroll 8
    for (int o = 0; o < NC2; ++o) {
        const float x = f2s[pl][o];
        #pragma unroll
        for (int r = 0; r < 4; ++r)
            a8[r] = fmaf(WC[q * 4 + r][o], x, a8[r]);
    }
    *(float4*)(VP8 + (pos0 + pl) * 8 + q * 4) = make_float4(a8[0], a8[1], a8[2], a8[3]);
}

// ---------------------------------------------------------------------------
// Kernel C: windowed attention from VP8 (unchanged).
// ---------------------------------------------------------------------------
__global__ __launch_bounds__(256) void attn_vp(
    const float* __restrict__ VP8,    // [NPOS][8]
    const float* __restrict__ out_b,  // [3]
    float* __restrict__ out)          // [3][NG]
{
    const int lo_t[12] = {0,1,5,9,14,18,22,26,31,35,39,44};
    const int hi_t[12] = {4,8,12,16,21,25,29,33,38,42,46,48};

    const int g    = blockIdx.x;
    const int tid  = threadIdx.x;
    const int lane = tid & 63;
    const int wv   = tid >> 6;

    const int gz = g % 12, gy = (g / 12) % 12, gx = g / 144;
    const int lox = lo_t[gx], hix = hi_t[gx];
    const int loy = lo_t[gy], hiy = hi_t[gy];
    const int loz = lo_t[gz], hiz = hi_t[gz];

    const float NEG_INF = -__builtin_inff();

    float4 lo0, hi0, lo1, hi1;
    {
        const int s = tid;
        const int kd = s / 49, kh = (s / 7) % 7, kw = s % 7;
        const int ix = lox + kd, iy = loy + kh, iz = loz + kw;
        if (ix < hix && iy < hiy && iz < hiz) {
            const int fv = (ix * DP + iy) * DP + iz;
            const float4* p = (const float4*)(VP8 + (size_t)fv * 8);
            lo0 = p[0]; hi0 = p[1];
        } else {
            lo0 = make_float4(NEG_INF, NEG_INF, 0.f, 0.f);
            hi0 = make_float4(0.f, 0.f, 0.f, 0.f);
        }
    }
    {
        const int s = tid + 256;
        lo1 = make_float4(NEG_INF, NEG_INF, 0.f, 0.f);
        hi1 = make_float4(0.f, 0.f, 0.f, 0.f);
        if (s < WIN3) {
            const int kd = s / 49, kh = (s / 7) % 7, kw = s % 7;
            const int ix = lox + kd, iy = loy + kh, iz = loz + kw;
            if (ix < hix && iy < hiy && iz < hiz) {
                const int fv = (ix * DP + iy) * DP + iz;
                const float4* p = (const float4*)(VP8 + (size_t)fv * 8);
                lo1 = p[0]; hi1 = p[1];
            }
        }
    }

    __shared__ float sred[4][8];

    float m0 = fmaxf(lo0.x, lo1.x);
    float m1 = fmaxf(lo0.y, lo1.y);
    #pragma unroll
    for (int off = 32; off; off >>= 1) {
        m0 = fmaxf(m0, __shfl_xor(m0, off));
        m1 = fmaxf(m1, __shfl_xor(m1, off));
    }
    if (lane == 0) { sred[wv][0] = m0; sred[wv][1] = m1; }
    __syncthreads();
    const float g0 = fmaxf(fmaxf(sred[0][0], sred[1][0]), fmaxf(sred[2][0], sred[3][0]));
    const float g1 = fmaxf(fmaxf(sred[0][1], sred[1][1]), fmaxf(sred[2][1], sred[3][1]));
    __syncthreads();

    const float e00 = expf(lo0.x - g0), e01 = expf(lo0.y - g1);
    const float e10 = expf(lo1.x - g0), e11 = expf(lo1.y - g1);

    float acc[8];
    acc[0] = e00 + e10;
    acc[1] = e01 + e11;
    acc[2] = e00 * lo0.z + e10 * lo1.z;
    acc[3] = e00 * lo0.w + e10 * lo1.w;
    acc[4] = e00 * hi0.x + e10 * hi1.x;
    acc[5] = e01 * hi0.y + e11 * hi1.y;
    acc[6] = e01 * hi0.z + e11 * hi1.z;
    acc[7] = e01 * hi0.w + e11 * hi1.w;

    #pragma unroll
    for (int j = 0; j < 8; ++j) {
        #pragma unroll
        for (int off = 32; off; off >>= 1) acc[j] += __shfl_xor(acc[j], off);
    }
    if (lane == 0) {
        #pragma unroll
        for (int j = 0; j < 8; ++j) sred[wv][j] = acc[j];
    }
    __syncthreads();

    if (tid < 3) {
        const float s0 = sred[0][0] + sred[1][0] + sred[2][0] + sred[3][0];
        const float s1 = sred[0][1] + sred[1][1] + sred[2][1] + sred[3][1];
        const float a0 = sred[0][2 + tid] + sred[1][2 + tid] + sred[2][2 + tid] + sred[3][2 + tid];
        const float a1 = sred[0][5 + tid] + sred[1][5 + tid] + sred[2][5 + tid] + sred[3][5 + tid];
        out[tid * NG + g] = out_b[tid] + a0 / s0 + a1 / s1;
    }
}

// ---------------------------------------------------------------------------
extern "C" void kernel_launch(void* const* d_in, const int* in_sizes, int n_in,
                              void* d_out, int out_size, void* d_ws, size_t ws_size,
                              hipStream_t stream) {
    const float* feat  = (const float*)d_in[0];
    const float* dw_w  = (const float*)d_in[1];
    const float* dw_b  = (const float*)d_in[2];
    const float* pw_w  = (const float*)d_in[3];
    const float* pw_b  = (const float*)d_in[4];
    const float* k_w   = (const float*)d_in[5];
    const float* v_w   = (const float*)d_in[6];
    const float* out_w = (const float*)d_in[7];
    const float* out_b = (const float*)d_in[8];
    float* out = (float*)d_out;

    __half* dwout = (__half*)d_ws;                              // [64][NPOS] 14 MB
    float*  VP8   = (float*)(dwout + (size_t)NCH * NPOS);       // [NPOS][8] 3.5 MB

    hipLaunchKernelGGL(dwconv8h, dim3(3456), dim3(256), 0, stream,
                       feat, dw_w, dw_b, dwout);
    hipLaunchKernelGGL(pwk, dim3(NPOS / 128), dim3(256), 0, stream,   // 864 blocks
                       dwout, pw_w, pw_b, k_w, v_w, out_w, VP8);
    hipLaunchKernelGGL(attn_vp, dim3(NG), dim3(256), 0, stream,
                       VP8, out_b, out);
}